// Round 1
// baseline (53113.965 us; speedup 1.0000x reference)
//
#include <hip/hip_runtime.h>
#include <hip/hip_bf16.h>

#define QD 1024
#define AD 26
#define BD 128
#define LD 1024

typedef short bf16x8 __attribute__((ext_vector_type(8)));
typedef float f32x4 __attribute__((ext_vector_type(4)));

static __device__ __forceinline__ unsigned short f2bf(float f) {
    __hip_bfloat16 h = __float2bfloat16(f);
    return *reinterpret_cast<unsigned short*>(&h);
}

// Row-softmax of trans_logits [1024,1024] -> bf16 packed in MFMA B-fragment order.
// Fragment layout for mfma_f32_16x16x32_bf16 B-operand:
//   B[k = quad*8 + j][n = nt*16 + col], lane = quad*16+col, frag elem j.
// tf index: ((kt*64 + nt)*64 + lane)*8 + j   for k = kt*32 + quad*8 + j.
__global__ void softmax_pack_T(const float* __restrict__ tl, unsigned short* __restrict__ tf) {
    const int i = blockIdx.x;      // T row (the K index of the scan matmul)
    const int tid = threadIdx.x;   // 256
    __shared__ float red[256];
    float v[4];
    float m = -1e30f;
    for (int c = 0; c < 4; ++c) { v[c] = tl[i * QD + tid + 256 * c]; m = fmaxf(m, v[c]); }
    red[tid] = m; __syncthreads();
    for (int s = 128; s > 0; s >>= 1) { if (tid < s) red[tid] = fmaxf(red[tid], red[tid + s]); __syncthreads(); }
    m = red[0]; __syncthreads();
    float sum = 0.f;
    for (int c = 0; c < 4; ++c) { v[c] = expf(v[c] - m); sum += v[c]; }
    red[tid] = sum; __syncthreads();
    for (int s = 128; s > 0; s >>= 1) { if (tid < s) red[tid] += red[tid + s]; __syncthreads(); }
    const float inv = 1.0f / red[0];
    const int kt = i >> 5, quad = (i >> 3) & 3, j = i & 7;
    for (int c = 0; c < 4; ++c) {
        const int q = tid + 256 * c;
        const int nt = q >> 4, col = q & 15;
        tf[(((kt * 64 + nt) * 64) + quad * 16 + col) * 8 + j] = f2bf(v[c] * inv);
    }
}

// Row-softmax of emis_logits [1024,26]; pack transposed (B[k=a][n=q]) into the same
// B-fragment order with K padded 26->32 with zeros. One ktile only.
__global__ void softmax_pack_B(const float* __restrict__ el, unsigned short* __restrict__ bmf) {
    const int q = blockIdx.x * blockDim.x + threadIdx.x;
    if (q >= QD) return;
    float v[AD];
    float m = -1e30f;
    for (int a = 0; a < AD; ++a) { v[a] = el[q * AD + a]; m = fmaxf(m, v[a]); }
    float sum = 0.f;
    for (int a = 0; a < AD; ++a) { v[a] = expf(v[a] - m); sum += v[a]; }
    const float inv = 1.0f / sum;
    const int nt = q >> 4, col = q & 15;
    for (int k = 0; k < 32; ++k) {
        const float val = (k < AD) ? v[k] * inv : 0.f;
        bmf[((nt * 64) + (k >> 3) * 16 + col) * 8 + (k & 7)] = f2bf(val);
    }
}

__global__ void softmax_pi(const float* __restrict__ il, float* __restrict__ pi) {
    const int tid = threadIdx.x;   // 1024
    __shared__ float red[1024];
    const float v = il[tid];
    red[tid] = v; __syncthreads();
    for (int s = 512; s > 0; s >>= 1) { if (tid < s) red[tid] = fmaxf(red[tid], red[tid + s]); __syncthreads(); }
    const float m = red[0]; __syncthreads();
    const float e = expf(v - m);
    red[tid] = e; __syncthreads();
    for (int s = 512; s > 0; s >>= 1) { if (tid < s) red[tid] += red[tid + s]; __syncthreads(); }
    pi[tid] = e / red[0];
}

// Scan kernel: grid=8 WGs, 256 threads (4 waves). WG handles 16 batch rows.
// Wave w owns ntiles [w*16, w*16+16) (256 of the 1024 output states).
// A-frag layout: A[m=lane&15][k=quad*8+j]. C/D: col=lane&15, row=quad*4+reg.
__launch_bounds__(256, 1)
__global__ void hmm_scan(const float* __restrict__ inputs,
                         const unsigned short* __restrict__ tf,
                         const unsigned short* __restrict__ bmf,
                         const float* __restrict__ pi,
                         float* __restrict__ out) {
    __shared__ unsigned short alpha[16][1032];   // normalized alpha, bf16, padded stride
    __shared__ unsigned short int_t[16][32];     // inputs[b, t, :] padded to 32, bf16
    __shared__ float pis[QD];
    __shared__ float s_lds[16];
    __shared__ float sinv[16];
    __shared__ float ll[16];

    const int tid  = threadIdx.x;
    const int wave = tid >> 6;
    const int lane = tid & 63;
    const int quad = lane >> 4;
    const int col  = lane & 15;
    const int b0   = blockIdx.x * 16;

    for (int i = tid; i < QD; i += 256) pis[i] = pi[i];
    if (tid < 16) ll[tid] = 0.f;

    const bf16x8* __restrict__ tfv = (const bf16x8*)tf;
    const bf16x8* __restrict__ bmv = (const bf16x8*)bmf;
    const f32x4 fzero = {0.f, 0.f, 0.f, 0.f};

    f32x4 e[16], acc[16];

    for (int t = 0; t < LD; ++t) {
        __syncthreads();  // alpha(t-1) writes visible; prior s_lds consumers done
        for (int idx = tid; idx < 16 * 32; idx += 256) {
            const int m = idx >> 5, k = idx & 31;
            const float v = (k < AD) ? inputs[((size_t)(b0 + m) * LD + t) * AD + k] : 0.f;
            int_t[m][k] = f2bf(v);
        }
        if (tid < 16) s_lds[tid] = 0.f;
        __syncthreads();

        // emissions e[b, q] = inputs[b,t,:] @ Bm^T  (one K=32 MFMA per ntile)
        bf16x8 ina = *(const bf16x8*)&int_t[col][quad * 8];
        #pragma unroll
        for (int nt = 0; nt < 16; ++nt) {
            bf16x8 b = bmv[(wave * 16 + nt) * 64 + lane];
            e[nt] = __builtin_amdgcn_mfma_f32_16x16x32_bf16(ina, b, fzero, 0, 0, 0);
        }

        if (t == 0) {
            #pragma unroll
            for (int nt = 0; nt < 16; ++nt) {
                const float pv = pis[(wave * 16 + nt) * 16 + col];
                #pragma unroll
                for (int r = 0; r < 4; ++r) acc[nt][r] = pv * e[nt][r];
            }
        } else {
            #pragma unroll
            for (int nt = 0; nt < 16; ++nt) acc[nt] = fzero;
            for (int kt = 0; kt < 32; ++kt) {
                bf16x8 a = *(const bf16x8*)&alpha[col][kt * 32 + quad * 8];
                #pragma unroll
                for (int nt = 0; nt < 16; ++nt) {
                    bf16x8 b = tfv[((kt * 64) + wave * 16 + nt) * 64 + lane];
                    acc[nt] = __builtin_amdgcn_mfma_f32_16x16x32_bf16(a, b, acc[nt], 0, 0, 0);
                }
            }
            #pragma unroll
            for (int nt = 0; nt < 16; ++nt)
                #pragma unroll
                for (int r = 0; r < 4; ++r) acc[nt][r] *= e[nt][r];
        }

        // per-batch-row sums: row = quad*4 + r
        float p[4] = {0.f, 0.f, 0.f, 0.f};
        #pragma unroll
        for (int nt = 0; nt < 16; ++nt)
            #pragma unroll
            for (int r = 0; r < 4; ++r) p[r] += acc[nt][r];
        #pragma unroll
        for (int r = 0; r < 4; ++r) {
            p[r] += __shfl_xor(p[r], 1);
            p[r] += __shfl_xor(p[r], 2);
            p[r] += __shfl_xor(p[r], 4);
            p[r] += __shfl_xor(p[r], 8);
        }
        if (col == 0) {
            #pragma unroll
            for (int r = 0; r < 4; ++r) atomicAdd(&s_lds[quad * 4 + r], p[r]);
        }
        __syncthreads();
        if (tid < 16) {
            const float sv = s_lds[tid];
            ll[tid] += logf(sv);
            sinv[tid] = 1.f / sv;
        }
        __syncthreads();
        // write normalized alpha (bf16) for next step
        #pragma unroll
        for (int r = 0; r < 4; ++r) {
            const float iv = sinv[quad * 4 + r];
            #pragma unroll
            for (int nt = 0; nt < 16; ++nt)
                alpha[quad * 4 + r][(wave * 16 + nt) * 16 + col] = f2bf(acc[nt][r] * iv);
        }
    }
    __syncthreads();
    if (tid < 16) out[b0 + tid] = ll[tid];
}

extern "C" void kernel_launch(void* const* d_in, const int* in_sizes, int n_in,
                              void* d_out, int out_size, void* d_ws, size_t ws_size,
                              hipStream_t stream) {
    const float* inputs       = (const float*)d_in[0];
    const float* init_logits  = (const float*)d_in[1];
    const float* trans_logits = (const float*)d_in[2];
    const float* emis_logits  = (const float*)d_in[3];
    float* out = (float*)d_out;

    unsigned short* tf  = (unsigned short*)d_ws;          // 1M bf16 = 2 MB
    unsigned short* bmf = tf + (size_t)QD * QD;           // 32768 bf16 = 64 KB
    float* pi           = (float*)(bmf + 64 * 512);       // 1024 f32

    softmax_pack_T<<<1024, 256, 0, stream>>>(trans_logits, tf);
    softmax_pack_B<<<4, 256, 0, stream>>>(emis_logits, bmf);
    softmax_pi<<<1, 1024, 0, stream>>>(init_logits, pi);
    hmm_scan<<<8, 256, 0, stream>>>(inputs, tf, bmf, pi, out);
}

// Round 2
// 39611.353 us; speedup vs baseline: 1.3409x; 1.3409x over previous
//
#include <hip/hip_runtime.h>
#include <hip/hip_bf16.h>
#include <hip/hip_cooperative_groups.h>

namespace cg = cooperative_groups;

#define QD 1024
#define AD 26
#define BD 128
#define LD 1024

typedef short bf16x8 __attribute__((ext_vector_type(8)));
typedef float f32x4 __attribute__((ext_vector_type(4)));

static __device__ __forceinline__ unsigned short f2bf(float f) {
    __hip_bfloat16 h = __float2bfloat16(f);
    return *reinterpret_cast<unsigned short*>(&h);
}

// Row-softmax of trans_logits [1024,1024] -> bf16 packed as A-fragments of T^T.
// A-frag layout (16x16x32): A[m = lane&15][k = quad*8 + j].
// For T element [i=q_in][c=q_out]: mt=c>>4, col=c&15, kt=i>>5, quad=(i>>3)&3, j=i&7.
// tf[((mt*32 + kt)*64 + quad*16 + col)*8 + j]
__global__ void softmax_pack_T(const float* __restrict__ tl, unsigned short* __restrict__ tf) {
    const int i = blockIdx.x;      // q_in (row of T; softmax is over q_out within row)
    const int tid = threadIdx.x;   // 256
    __shared__ float red[256];
    float v[4];
    float m = -1e30f;
    for (int c = 0; c < 4; ++c) { v[c] = tl[i * QD + tid + 256 * c]; m = fmaxf(m, v[c]); }
    red[tid] = m; __syncthreads();
    for (int s = 128; s > 0; s >>= 1) { if (tid < s) red[tid] = fmaxf(red[tid], red[tid + s]); __syncthreads(); }
    m = red[0]; __syncthreads();
    float sum = 0.f;
    for (int c = 0; c < 4; ++c) { v[c] = expf(v[c] - m); sum += v[c]; }
    red[tid] = sum; __syncthreads();
    for (int s = 128; s > 0; s >>= 1) { if (tid < s) red[tid] += red[tid + s]; __syncthreads(); }
    const float inv = 1.0f / red[0];
    const int kt = i >> 5, quad = (i >> 3) & 3, j = i & 7;
    for (int c = 0; c < 4; ++c) {
        const int q = tid + 256 * c;
        const int mt = q >> 4, col = q & 15;
        tf[(size_t)((mt * 32 + kt) * 64 + quad * 16 + col) * 8 + j] = f2bf(v[c] * inv);
    }
}

// Row-softmax of emis_logits [1024,26] -> bf16 packed as A-fragments (M=q, K=a pad 32).
// bmf[((q>>4)*64 + (a>>3)*16 + (q&15))*8 + (a&7)]
__global__ void softmax_pack_B(const float* __restrict__ el, unsigned short* __restrict__ bmf) {
    const int q = blockIdx.x * blockDim.x + threadIdx.x;
    if (q >= QD) return;
    float v[AD];
    float m = -1e30f;
    for (int a = 0; a < AD; ++a) { v[a] = el[q * AD + a]; m = fmaxf(m, v[a]); }
    float sum = 0.f;
    for (int a = 0; a < AD; ++a) { v[a] = expf(v[a] - m); sum += v[a]; }
    const float inv = 1.0f / sum;
    const int mt = q >> 4, col = q & 15;
    for (int a = 0; a < 32; ++a) {
        const float val = (a < AD) ? v[a] * inv : 0.f;
        bmf[(size_t)(mt * 64 + (a >> 3) * 16 + col) * 8 + (a & 7)] = f2bf(val);
    }
}

__global__ void softmax_pi(const float* __restrict__ il, float* __restrict__ pi) {
    const int tid = threadIdx.x;   // 1024
    __shared__ float red[1024];
    const float v = il[tid];
    red[tid] = v; __syncthreads();
    for (int s = 512; s > 0; s >>= 1) { if (tid < s) red[tid] = fmaxf(red[tid], red[tid + s]); __syncthreads(); }
    const float m = red[0]; __syncthreads();
    const float e = expf(v - m);
    red[tid] = e; __syncthreads();
    for (int s = 512; s > 0; s >>= 1) { if (tid < s) red[tid] += red[tid + s]; __syncthreads(); }
    pi[tid] = e / red[0];
}

// Cooperative scan: 128 WGs x 256 threads. WG = (qs = blockIdx>>2: 32 q_out) x
// (bg = blockIdx&3: 32 batches). T^T slice [32 q_out x 1024 q_in] lives in LDS
// for the whole scan. Orientation: M=q_out, N=batch, K=q_in.
// Deferred normalization: alpha stored unnormalized; step t scales by 1/c_{t-1}
// where c_t = sum_q alpha_t (atomics into sbuf[t][b]); c_t == reference s_t.
__launch_bounds__(256)
__global__ void hmm_scan(const float* __restrict__ inputs,
                         const unsigned short* __restrict__ tf,
                         const unsigned short* __restrict__ bmf,
                         const float* __restrict__ pi,
                         unsigned short* __restrict__ abuf,   // 2 x [BD][QD] bf16
                         float* __restrict__ sbuf,            // [LD][BD] f32, zeroed
                         float* __restrict__ out) {
    __shared__ unsigned short ts[2 * 32 * 64 * 8];   // 64 KB: T^T A-frags, [mtl][kt][lane][j]
    __shared__ unsigned short int_t[32 * 32];        // inputs[b0..+32][t][a] bf16, pad 32
    __shared__ float part[32];

    const int tid  = threadIdx.x;
    const int wave = tid >> 6;
    const int lane = tid & 63;
    const int quad = lane >> 4;
    const int col  = lane & 15;
    const int mtl  = wave & 1;        // local q_out tile (0..1)
    const int ntl  = wave >> 1;       // local batch tile (0..1)
    const int qs   = blockIdx.x >> 2; // q-slice (0..31)
    const int bg   = blockIdx.x & 3;  // batch-group (0..3)
    const int b0   = bg * 32;
    const int bl   = ntl * 16 + col;  // local batch (0..31)
    const int b    = b0 + bl;         // global batch
    const int qrow = qs * 32 + mtl * 16 + quad * 4;  // q_out of acc reg r base

    cg::grid_group grid = cg::this_grid();

    // Load this WG's T^T slice (contiguous 64 KB) into LDS.
    {
        const float4* src = (const float4*)(tf + (size_t)(qs * 2) * 32 * 64 * 8);
        float4* dst = (float4*)ts;
        for (int i = tid; i < 4096; i += 256) dst[i] = src[i];
    }
    // Emission A-frag (constant) and pi for this wave's rows.
    const bf16x8 bmA = *(const bf16x8*)&bmf[(size_t)((qs * 2 + mtl) * 64 + lane) * 8];
    float pr[4];
    #pragma unroll
    for (int r = 0; r < 4; ++r) pr[r] = pi[qrow + r];

    const f32x4 fz = {0.f, 0.f, 0.f, 0.f};
    float ll = 0.f;

    for (int t = 0; t < LD; ++t) {
        if (tid < 32) part[tid] = 0.f;
        // Stage inputs[b0..b0+32][t][:] (pad 26->32 with zeros).
        for (int idx = tid; idx < 32 * 32; idx += 256) {
            const int row = idx >> 5, a = idx & 31;
            const float v = (a < AD) ? inputs[((size_t)(b0 + row) * LD + t) * AD + a] : 0.f;
            int_t[idx] = f2bf(v);
        }

        f32x4 acc0 = fz, acc1 = fz;
        float invc = 1.f;
        if (t > 0) {
            invc = 1.f / sbuf[(size_t)(t - 1) * BD + b];
            const unsigned short* arow =
                abuf + (size_t)((t + 1) & 1) * BD * QD + (size_t)b * QD + quad * 8;
            #pragma unroll 8
            for (int kt = 0; kt < 32; kt += 2) {
                bf16x8 af0 = *(const bf16x8*)&ts[(size_t)((mtl * 32 + kt) * 64 + lane) * 8];
                bf16x8 bf0 = *(const bf16x8*)&arow[(size_t)kt * 32];
                acc0 = __builtin_amdgcn_mfma_f32_16x16x32_bf16(af0, bf0, acc0, 0, 0, 0);
                bf16x8 af1 = *(const bf16x8*)&ts[(size_t)((mtl * 32 + kt + 1) * 64 + lane) * 8];
                bf16x8 bf1 = *(const bf16x8*)&arow[(size_t)(kt + 1) * 32];
                acc1 = __builtin_amdgcn_mfma_f32_16x16x32_bf16(af1, bf1, acc1, 0, 0, 0);
            }
        }
        __syncthreads();   // int_t staged; part zeroed

        // Emission: e[q_out, b] for this wave's tile.
        bf16x8 xB = *(const bf16x8*)&int_t[bl * 32 + quad * 8];
        f32x4 e = __builtin_amdgcn_mfma_f32_16x16x32_bf16(bmA, xB, fz, 0, 0, 0);

        float val[4];
        if (t == 0) {
            #pragma unroll
            for (int r = 0; r < 4; ++r) val[r] = pr[r] * e[r];
        } else {
            #pragma unroll
            for (int r = 0; r < 4; ++r) val[r] = (acc0[r] + acc1[r]) * e[r] * invc;
        }

        // Write alpha_t slice (row-major [b][q], bf16, 8B per lane).
        ushort4 st;
        st.x = f2bf(val[0]); st.y = f2bf(val[1]); st.z = f2bf(val[2]); st.w = f2bf(val[3]);
        unsigned short* aw = abuf + (size_t)(t & 1) * BD * QD;
        *reinterpret_cast<ushort4*>(&aw[(size_t)b * QD + qrow]) = st;

        // c_t partial: sum over this WG's 32 q for each batch.
        float p = val[0] + val[1] + val[2] + val[3];
        p += __shfl_xor(p, 16);
        p += __shfl_xor(p, 32);
        if (lane < 16) atomicAdd(&part[bl], p);
        __syncthreads();
        if (tid < 32) atomicAdd(&sbuf[(size_t)t * BD + b0 + tid], part[tid]);

        // Log-lik accumulation (one q-slice's blocks own it).
        if (qs == 0 && tid < 32 && t > 0) ll += logf(sbuf[(size_t)(t - 1) * BD + b0 + tid]);

        __threadfence();
        grid.sync();
        __threadfence();
    }

    if (qs == 0 && tid < 32)
        out[b0 + tid] = ll + logf(sbuf[(size_t)(LD - 1) * BD + b0 + tid]);
}

extern "C" void kernel_launch(void* const* d_in, const int* in_sizes, int n_in,
                              void* d_out, int out_size, void* d_ws, size_t ws_size,
                              hipStream_t stream) {
    const float* inputs       = (const float*)d_in[0];
    const float* init_logits  = (const float*)d_in[1];
    const float* trans_logits = (const float*)d_in[2];
    const float* emis_logits  = (const float*)d_in[3];
    float* out = (float*)d_out;

    unsigned short* tf  = (unsigned short*)d_ws;                 // 1M bf16 = 2 MB
    unsigned short* bmf = tf + (size_t)QD * QD;                  // 32K bf16 = 64 KB
    float* pi           = (float*)(bmf + (size_t)QD * 32);       // 4 KB
    unsigned short* ab  = (unsigned short*)(pi + QD);            // 2x128x1024 bf16 = 512 KB
    float* sbuf         = (float*)(ab + (size_t)2 * BD * QD);    // 1024x128 f32 = 512 KB

    hipMemsetAsync(sbuf, 0, (size_t)LD * BD * sizeof(float), stream);

    softmax_pack_T<<<1024, 256, 0, stream>>>(trans_logits, tf);
    softmax_pack_B<<<4, 256, 0, stream>>>(emis_logits, bmf);
    softmax_pi<<<1, 1024, 0, stream>>>(init_logits, pi);

    void* args[] = {(void*)&inputs, (void*)&tf, (void*)&bmf, (void*)&pi,
                    (void*)&ab, (void*)&sbuf, (void*)&out};
    hipLaunchCooperativeKernel((const void*)hmm_scan, dim3(128), dim3(256),
                               args, 0, stream);
}

// Round 3
// 17267.903 us; speedup vs baseline: 3.0759x; 2.2939x over previous
//
#include <hip/hip_runtime.h>
#include <hip/hip_bf16.h>

#define QD 1024
#define AD 26
#define BD 128
#define LD 1024
#define NWG 64

typedef short bf16x8 __attribute__((ext_vector_type(8)));
typedef float f32x4 __attribute__((ext_vector_type(4)));

static __device__ __forceinline__ unsigned short f2bf(float f) {
    __hip_bfloat16 h = __float2bfloat16(f);
    return *reinterpret_cast<unsigned short*>(&h);
}

// Row-softmax of trans_logits [1024,1024] -> bf16 packed as A-fragments of T^T.
// A-frag layout (16x16x32): A[m = lane&15][k = quad*8 + j].
// For T element [i=q_in][c=q_out]: mt=c>>4, col=c&15, kt=i>>5, quad=(i>>3)&3, j=i&7.
// tf[((mt*32 + kt)*64 + quad*16 + col)*8 + j]
__global__ void softmax_pack_T(const float* __restrict__ tl, unsigned short* __restrict__ tf) {
    const int i = blockIdx.x;      // q_in (row of T; softmax is over q_out within row)
    const int tid = threadIdx.x;   // 256
    __shared__ float red[256];
    float v[4];
    float m = -1e30f;
    for (int c = 0; c < 4; ++c) { v[c] = tl[i * QD + tid + 256 * c]; m = fmaxf(m, v[c]); }
    red[tid] = m; __syncthreads();
    for (int s = 128; s > 0; s >>= 1) { if (tid < s) red[tid] = fmaxf(red[tid], red[tid + s]); __syncthreads(); }
    m = red[0]; __syncthreads();
    float sum = 0.f;
    for (int c = 0; c < 4; ++c) { v[c] = expf(v[c] - m); sum += v[c]; }
    red[tid] = sum; __syncthreads();
    for (int s = 128; s > 0; s >>= 1) { if (tid < s) red[tid] += red[tid + s]; __syncthreads(); }
    const float inv = 1.0f / red[0];
    const int kt = i >> 5, quad = (i >> 3) & 3, j = i & 7;
    for (int c = 0; c < 4; ++c) {
        const int q = tid + 256 * c;
        const int mt = q >> 4, col = q & 15;
        tf[(size_t)((mt * 32 + kt) * 64 + quad * 16 + col) * 8 + j] = f2bf(v[c] * inv);
    }
}

// Row-softmax of emis_logits [1024,26] -> bf16 packed as A-fragments (M=q, K=a pad 32).
__global__ void softmax_pack_B(const float* __restrict__ el, unsigned short* __restrict__ bmf) {
    const int q = blockIdx.x * blockDim.x + threadIdx.x;
    if (q >= QD) return;
    float v[AD];
    float m = -1e30f;
    for (int a = 0; a < AD; ++a) { v[a] = el[q * AD + a]; m = fmaxf(m, v[a]); }
    float sum = 0.f;
    for (int a = 0; a < AD; ++a) { v[a] = expf(v[a] - m); sum += v[a]; }
    const float inv = 1.0f / sum;
    const int mt = q >> 4, col = q & 15;
    for (int a = 0; a < 32; ++a) {
        const float val = (a < AD) ? v[a] * inv : 0.f;
        bmf[(size_t)(mt * 64 + (a >> 3) * 16 + col) * 8 + (a & 7)] = f2bf(val);
    }
}

__global__ void softmax_pi(const float* __restrict__ il, float* __restrict__ pi) {
    const int tid = threadIdx.x;   // 1024
    __shared__ float red[1024];
    const float v = il[tid];
    red[tid] = v; __syncthreads();
    for (int s = 512; s > 0; s >>= 1) { if (tid < s) red[tid] = fmaxf(red[tid], red[tid + s]); __syncthreads(); }
    const float m = red[0]; __syncthreads();
    const float e = expf(v - m);
    red[tid] = e; __syncthreads();
    for (int s = 512; s > 0; s >>= 1) { if (tid < s) red[tid] += red[tid + s]; __syncthreads(); }
    pi[tid] = e / red[0];
}

// Cooperative scan: 64 WGs x 256 threads. WG = (qs = blockIdx>>1: 32 q_out) x
// (bg = blockIdx&1: 64 batches). T^T slice [32 q_out x 1024 q_in] = 64 KB LDS.
// Wave roles: mtl = wave&1 (m-tile), bhalf = wave>>1 (which 32 of the 64 batches).
// Normalization is consumer-side: c_{t-1}[b] = sum_q alpha_hat_{t-1}[b][q] computed
// by every WG from the alpha it reads anyway, via ones-A MFMA chains. Deterministic
// and identical across WGs. No global sum, nothing read after the barrier.
// Custom grid barrier: monotone counter, release-add + relaxed spin + acquire load.
__launch_bounds__(256)
__global__ void hmm_scan(const float* __restrict__ inputs,
                         const unsigned short* __restrict__ tf,
                         const unsigned short* __restrict__ bmf,
                         const float* __restrict__ pi,
                         unsigned short* __restrict__ abuf,   // 2 x [BD][QD] bf16
                         unsigned int* __restrict__ bar,      // zeroed
                         float* __restrict__ out) {
    __shared__ unsigned short ts[2 * 32 * 64 * 8];   // 64 KB T^T A-frags
    __shared__ unsigned short int_t[64 * 32];        // inputs[b][a] bf16, pad 32
    __shared__ float cbuf[64];

    const int tid   = threadIdx.x;
    const int wave  = tid >> 6;
    const int lane  = tid & 63;
    const int quad  = lane >> 4;
    const int col   = lane & 15;
    const int mtl   = wave & 1;
    const int bhalf = wave >> 1;
    const int qs    = (int)blockIdx.x >> 1;
    const int bg    = (int)blockIdx.x & 1;
    const int bbase = bg * 64 + bhalf * 32;          // first batch of this wave's group
    const int qrow  = qs * 32 + mtl * 16 + quad * 4; // q_out row of acc reg 0

    // Load T^T slice (contiguous 64 KB) into LDS.
    {
        const float4* src = (const float4*)(tf + (size_t)(qs * 2) * 32 * 64 * 8);
        float4* dst = (float4*)ts;
        for (int i = tid; i < 4096; i += 256) dst[i] = src[i];
    }
    const bf16x8 bmA = *(const bf16x8*)&bmf[(size_t)((qs * 2 + mtl) * 64 + lane) * 8];
    float pr[4];
    #pragma unroll
    for (int r = 0; r < 4; ++r) pr[r] = pi[qrow + r];

    bf16x8 ones;
    #pragma unroll
    for (int i = 0; i < 8; ++i) ones[i] = (short)0x3F80;

    const f32x4 fz = {0.f, 0.f, 0.f, 0.f};
    float ll = 0.f;

    for (int t = 0; t < LD; ++t) {
        // Stage inputs[bg*64 .. +64][t][:] (pad 26->32).
        for (int idx = tid; idx < 64 * 32; idx += 256) {
            const int row = idx >> 5, a = idx & 31;
            const float v = (a < AD) ? inputs[((size_t)(bg * 64 + row) * LD + t) * AD + a] : 0.f;
            int_t[idx] = f2bf(v);
        }

        f32x4 acc0 = fz, acc1 = fz, on0 = fz, on1 = fz;
        if (t > 0) {
            const unsigned short* ab = abuf + (size_t)((t + 1) & 1) * BD * QD;
            const unsigned short* arow0 = ab + (size_t)(bbase + col) * QD + quad * 8;
            const unsigned short* arow1 = ab + (size_t)(bbase + 16 + col) * QD + quad * 8;
            #pragma unroll 8
            for (int kt = 0; kt < 32; ++kt) {
                bf16x8 af = *(const bf16x8*)&ts[(size_t)((mtl * 32 + kt) * 64 + lane) * 8];
                bf16x8 b0 = *(const bf16x8*)&arow0[(size_t)kt * 32];
                bf16x8 b1 = *(const bf16x8*)&arow1[(size_t)kt * 32];
                acc0 = __builtin_amdgcn_mfma_f32_16x16x32_bf16(af, b0, acc0, 0, 0, 0);
                acc1 = __builtin_amdgcn_mfma_f32_16x16x32_bf16(af, b1, acc1, 0, 0, 0);
                on0  = __builtin_amdgcn_mfma_f32_16x16x32_bf16(ones, b0, on0, 0, 0, 0);
                on1  = __builtin_amdgcn_mfma_f32_16x16x32_bf16(ones, b1, on1, 0, 0, 0);
            }
        }
        __syncthreads();   // int_t staged

        // Emissions for this wave's m-tile x two n-tiles.
        bf16x8 x0 = *(const bf16x8*)&int_t[(bhalf * 32 + col) * 32 + quad * 8];
        bf16x8 x1 = *(const bf16x8*)&int_t[(bhalf * 32 + 16 + col) * 32 + quad * 8];
        f32x4 e0 = __builtin_amdgcn_mfma_f32_16x16x32_bf16(bmA, x0, fz, 0, 0, 0);
        f32x4 e1 = __builtin_amdgcn_mfma_f32_16x16x32_bf16(bmA, x1, fz, 0, 0, 0);

        float v0[4], v1[4];
        if (t == 0) {
            #pragma unroll
            for (int r = 0; r < 4; ++r) { v0[r] = pr[r] * e0[r]; v1[r] = pr[r] * e1[r]; }
        } else {
            const float i0 = 1.f / on0[0], i1 = 1.f / on1[0];
            #pragma unroll
            for (int r = 0; r < 4; ++r) { v0[r] = acc0[r] * e0[r] * i0; v1[r] = acc1[r] * e1[r] * i1; }
        }

        // Write alpha_t slice ([b][q] bf16, 8 B/lane/n-tile).
        unsigned short* aw = abuf + (size_t)(t & 1) * BD * QD;
        ushort4 s0, s1;
        s0.x = f2bf(v0[0]); s0.y = f2bf(v0[1]); s0.z = f2bf(v0[2]); s0.w = f2bf(v0[3]);
        s1.x = f2bf(v1[0]); s1.y = f2bf(v1[1]); s1.z = f2bf(v1[2]); s1.w = f2bf(v1[3]);
        *reinterpret_cast<ushort4*>(&aw[(size_t)(bbase + col) * QD + qrow]) = s0;
        *reinterpret_cast<ushort4*>(&aw[(size_t)(bbase + 16 + col) * QD + qrow]) = s1;

        // Share c_{t-1} within the WG for loglik accumulation.
        if (t > 0 && mtl == 0 && quad == 0) {
            cbuf[bhalf * 32 + col] = on0[0];
            cbuf[bhalf * 32 + 16 + col] = on1[0];
        }
        __syncthreads();   // cbuf ready; s_barrier drains alpha stores (vmcnt)
        if (t > 0 && tid < 64) ll += logf(cbuf[tid]);

        // Grid barrier: release-add, relaxed spin, acquire.
        if (tid == 0) {
            __hip_atomic_fetch_add(bar, 1u, __ATOMIC_RELEASE, __HIP_MEMORY_SCOPE_AGENT);
            const unsigned target = (unsigned)(t + 1) * NWG;
            while (__hip_atomic_load(bar, __ATOMIC_RELAXED, __HIP_MEMORY_SCOPE_AGENT) < target)
                __builtin_amdgcn_s_sleep(1);
            (void)__hip_atomic_load(bar, __ATOMIC_ACQUIRE, __HIP_MEMORY_SCOPE_AGENT);
        }
        __syncthreads();
    }

    // Final normalizer c_{L-1} for loglik.
    if (qs == 0) {
        const unsigned short* ab = abuf + (size_t)((LD - 1) & 1) * BD * QD;
        const unsigned short* arow0 = ab + (size_t)(bbase + col) * QD + quad * 8;
        const unsigned short* arow1 = ab + (size_t)(bbase + 16 + col) * QD + quad * 8;
        f32x4 on0 = fz, on1 = fz;
        #pragma unroll 8
        for (int kt = 0; kt < 32; ++kt) {
            bf16x8 b0 = *(const bf16x8*)&arow0[(size_t)kt * 32];
            bf16x8 b1 = *(const bf16x8*)&arow1[(size_t)kt * 32];
            on0 = __builtin_amdgcn_mfma_f32_16x16x32_bf16(ones, b0, on0, 0, 0, 0);
            on1 = __builtin_amdgcn_mfma_f32_16x16x32_bf16(ones, b1, on1, 0, 0, 0);
        }
        if (mtl == 0 && quad == 0) {
            cbuf[bhalf * 32 + col] = on0[0];
            cbuf[bhalf * 32 + 16 + col] = on1[0];
        }
    }
    __syncthreads();
    if (qs == 0 && tid < 64) out[bg * 64 + tid] = ll + logf(cbuf[tid]);
}

extern "C" void kernel_launch(void* const* d_in, const int* in_sizes, int n_in,
                              void* d_out, int out_size, void* d_ws, size_t ws_size,
                              hipStream_t stream) {
    const float* inputs       = (const float*)d_in[0];
    const float* init_logits  = (const float*)d_in[1];
    const float* trans_logits = (const float*)d_in[2];
    const float* emis_logits  = (const float*)d_in[3];
    float* out = (float*)d_out;

    unsigned short* tf  = (unsigned short*)d_ws;                 // 2 MB
    unsigned short* bmf = tf + (size_t)QD * QD;                  // 64 KB
    float* pi           = (float*)(bmf + (size_t)QD * 32);       // 4 KB
    unsigned short* ab  = (unsigned short*)(pi + QD);            // 512 KB
    unsigned int* bar   = (unsigned int*)(ab + (size_t)2 * BD * QD);

    hipMemsetAsync(bar, 0, sizeof(unsigned int), stream);

    softmax_pack_T<<<1024, 256, 0, stream>>>(trans_logits, tf);
    softmax_pack_B<<<4, 256, 0, stream>>>(emis_logits, bmf);
    softmax_pi<<<1, 1024, 0, stream>>>(init_logits, pi);

    void* args[] = {(void*)&inputs, (void*)&tf, (void*)&bmf, (void*)&pi,
                    (void*)&ab, (void*)&bar, (void*)&out};
    hipLaunchCooperativeKernel((const void*)hmm_scan, dim3(NWG), dim3(256),
                               args, 0, stream);
}